// Round 3
// baseline (506.425 us; speedup 1.0000x reference)
//
#include <hip/hip_runtime.h>
#include <hip/hip_bf16.h>
#include <math.h>

typedef __attribute__((ext_vector_type(4))) float  f32x4;
typedef __attribute__((ext_vector_type(4))) int    i32x4;
typedef __attribute__((ext_vector_type(8))) short  s16x8;
typedef __attribute__((ext_vector_type(4))) short  s16x4;
typedef __attribute__((ext_vector_type(8))) __bf16 bf16x8;

#define LOG2E 1.4426950408889634f

__device__ __forceinline__ short f32_to_bf16_rne(float f) {
    unsigned u = __builtin_bit_cast(unsigned, f);
    u += 0x7fffu + ((u >> 16) & 1u);
    return (short)(u >> 16);
}
__device__ __forceinline__ int pack2_bf16(float f0, float f1) {
    unsigned u0 = __builtin_bit_cast(unsigned, f0) + 0x8000u;   // round-half-up
    unsigned u1 = __builtin_bit_cast(unsigned, f1) + 0x8000u;
    return (int)((u0 >> 16) | (u1 & 0xffff0000u));
}
__device__ __forceinline__ bf16x8 as_bf16x8(s16x8 v) {
    return __builtin_bit_cast(bf16x8, v);
}
__device__ __forceinline__ bf16x8 as_bf16x8(i32x4 v) {
    return __builtin_bit_cast(bf16x8, v);
}

// ---------------- k0: W (f32 [k][col]) -> WT bf16 [col][k] ----------------
__global__ void k0_wt(const float* __restrict__ W, short* __restrict__ WT) {
    int g = blockIdx.x * 256 + threadIdx.x;     // 0..8191
    int col = g >> 6;
    int k0 = (g & 63) * 4;
    s16x4 v;
    #pragma unroll
    for (int i = 0; i < 4; ++i) v[i] = f32_to_bf16_rne(W[(k0 + i) * 128 + col]);
    *(s16x4*)(WT + col * 256 + k0) = v;
}

// ---------------- k1: Wh = h@W (MFMA), emit WhT bf16 [b][col][n], Wh1', Wh2' ----------------
__global__ __launch_bounds__(256, 2) void k1_gemm(
    const float* __restrict__ h, const float* __restrict__ a,
    const short* __restrict__ WT,
    short* __restrict__ WhT, float* __restrict__ Wh1p, float* __restrict__ Tp)
{
    int l = threadIdx.x & 63;
    int w = threadIdx.x >> 6;
    int gw = blockIdx.x * 4 + w;
    int r0 = gw * 16;                  // global row base (b*4096+n), multiple of 16
    int lm = l & 15, q = l >> 4;

    f32x4 acc[8];
    #pragma unroll
    for (int ct = 0; ct < 8; ++ct) acc[ct] = (f32x4)0.0f;

    const float* hrow = h + (long)(r0 + lm) * 256;
    for (int kb = 0; kb < 8; ++kb) {
        int kbase = kb * 32 + q * 8;
        f32x4 h0 = *(const f32x4*)(hrow + kbase);
        f32x4 h1 = *(const f32x4*)(hrow + kbase + 4);
        s16x8 af;
        #pragma unroll
        for (int j = 0; j < 4; ++j) af[j] = f32_to_bf16_rne(h0[j]);
        #pragma unroll
        for (int j = 0; j < 4; ++j) af[4 + j] = f32_to_bf16_rne(h1[j]);
        bf16x8 afb = as_bf16x8(af);
        #pragma unroll
        for (int ct = 0; ct < 8; ++ct) {
            s16x8 bf = *(const s16x8*)(WT + (ct * 16 + lm) * 256 + kbase);
            acc[ct] = __builtin_amdgcn_mfma_f32_16x16x32_bf16(afb, as_bf16x8(bf), acc[ct], 0, 0, 0);
        }
    }

    int b = r0 >> 12;
    int nb = r0 & 4095;
    float p1[4] = {0.f, 0.f, 0.f, 0.f}, p2[4] = {0.f, 0.f, 0.f, 0.f};
    #pragma unroll
    for (int ct = 0; ct < 8; ++ct) {
        int col = ct * 16 + lm;
        float a1c = a[col], a2c = a[128 + col];
        s16x4 vv;
        #pragma unroll
        for (int r = 0; r < 4; ++r) {
            float v = acc[ct][r];
            p1[r] += v * a1c;
            p2[r] += v * a2c;
            vv[r] = f32_to_bf16_rne(v);
        }
        *(s16x4*)(WhT + ((long)(b * 128 + col) * 4096 + nb + q * 4)) = vv;
    }
    #pragma unroll
    for (int off = 1; off < 16; off <<= 1) {
        #pragma unroll
        for (int r = 0; r < 4; ++r) {
            p1[r] += __shfl_xor(p1[r], off);
            p2[r] += __shfl_xor(p2[r], off);
        }
    }
    if (lm == 0) {
        #pragma unroll
        for (int r = 0; r < 4; ++r) {
            int row = r0 + q * 4 + r;
            Wh1p[row] = LOG2E * p1[r];
            Tp[row]   = LOG2E * p2[r];
        }
    }
}

// ---------------- k2: per-batch max of Tp ----------------
__global__ void k2_tmax(const float* __restrict__ Tp, float* __restrict__ Tmax) {
    __shared__ float red[256];
    int b = blockIdx.x, t = threadIdx.x;
    float mx = -1e30f;
    for (int i = 0; i < 16; ++i) mx = fmaxf(mx, Tp[b * 4096 + t + i * 256]);
    red[t] = mx;
    __syncthreads();
    for (int s = 128; s > 0; s >>= 1) {
        if (t < s) red[t] = fmaxf(red[t], red[t + s]);
        __syncthreads();
    }
    if (t == 0) Tmax[b] = red[0];
}

// ---------------- k3: BARRIER-FREE per-wave attention --------------------------
// Round-2 counters: k3 167us, MfmaUtil 4%, VALUBusy 13.5%, 2.37 TB/s (30% peak)
// -- every pipe idle => the per-tile __syncthreads vmcnt(0) drain of HBM-latency
// adj prefetches was the stall, and LDS B-staging is what forced the barrier.
// WhT's per-block slice is 256 KB and L2-resident (FETCH ~= adj alone), so B
// fragments are now read straight from L2 into registers; the compiler emits
// COUNTED vmcnt waits for register loads, so nothing ever drains to 0. Each
// wave runs its 16 n-rows x 1024 m-slice fully independently:
//   iter(32 m): [issue B(t+1) from L2] [issue adj(t+4) from HBM] compute(t)
// adj is prefetched 4 iterations deep (~3 iter lead > 900cy HBM latency).
// Only LDS use is a 4 KB Tp slice staged once (single barrier, then free-run).
// bid&15 = (b,mh): round-robin block->XCD keeps each XCD on 2 WhT slices
// (512 KB, L2-resident); adj streams through.
template <int SPLIT>
__global__ __launch_bounds__(256, 4) void k3_attn(
    const int* __restrict__ adj, const short* __restrict__ WhT,
    const float* __restrict__ Wh1p, const float* __restrict__ Tp,
    const float* __restrict__ Tmax,
    float* __restrict__ U, float* __restrict__ Z)
{
    const int MSLICE = 4096 / SPLIT;       // 1024
    const int MITERS = MSLICE / 32;        // 32
    const int MM = MSLICE - 1;             // wrap mask keeps prefetch in-slice
    __shared__ __align__(16) float tps[4096 / SPLIT];    // 4 KB Tp slice

    int l = threadIdx.x & 63, w = threadIdx.x >> 6;
    int lm = l & 15, q = l >> 4;
    int bid = blockIdx.x;
    int p = bid & (4 * SPLIT - 1);         // (b, mh); 16 combos -> 2 per XCD
    int b  = p / SPLIT;                    // batch 0..3
    int mh = p & (SPLIT - 1);              // m-quarter 0..3
    int rg = bid / (4 * SPLIT);            // row-group 0..63
    int n0 = rg * 64;
    int mbase = mh * MSLICE;

    int n_lane = n0 + w * 16 + lm;
    float sp = Wh1p[b * 4096 + n_lane];
    float xm = sp + Tmax[b];
    float Mrow = fmaxf(xm, 0.2f * xm);

    const int*   adjrow = adj + ((long)(b * 4096 + n_lane) << 12) + q * 8;
    const short* wcol   = WhT + (long)b * 128 * 4096 + (long)lm * 4096 + q * 8;
    const float* tpsq   = tps + q * 8;

    // stage Tp slice to LDS (once): 1024 floats, one f32x4 per thread
    {
        const float* tg = Tp + b * 4096 + mbase;
        int i0 = threadIdx.x * 4;
        *(f32x4*)(tps + i0) = *(const f32x4*)(tg + i0);
    }
    __syncthreads();                       // only barrier in the kernel

    f32x4 acc[8];
    #pragma unroll
    for (int ct = 0; ct < 8; ++ct) acc[ct] = (f32x4)0.0f;
    float z = 0.0f;

    auto ldB = [&](s16x8* Bf, int m) {     // B-frags for one 32-m step (L2)
        #pragma unroll
        for (int ct = 0; ct < 8; ++ct)
            Bf[ct] = *(const s16x8*)(wcol + (long)ct * 65536 + m);
    };
    auto ldA = [&](i32x4* av, int m) {     // adjacency for one 32-m step (HBM)
        av[0] = *(const i32x4*)(adjrow + m);
        av[1] = *(const i32x4*)(adjrow + m + 4);
    };
    auto compute = [&](const s16x8* Bf, const i32x4* av, int mrel) {
        f32x4 t0 = *(const f32x4*)(tpsq + mrel);
        f32x4 t1 = *(const f32x4*)(tpsq + mrel + 4);
        i32x4 pk;
        float zs = 0.0f;
        #pragma unroll
        for (int half = 0; half < 2; ++half) {
            i32x4 a4 = av[half];
            f32x4 t4 = half ? t1 : t0;
            float wv[4];
            #pragma unroll
            for (int j = 0; j < 4; ++j) {
                float y = sp + t4[j];
                float e = fmaxf(y, 0.2f * y) - Mrow;
                float v = __builtin_amdgcn_exp2f(e);
                v = (a4[j] != 0) ? v : 0.0f;
                zs += v; wv[j] = v;
            }
            pk[half * 2]     = pack2_bf16(wv[0], wv[1]);
            pk[half * 2 + 1] = pack2_bf16(wv[2], wv[3]);
        }
        z += zs;
        bf16x8 ab = as_bf16x8(pk);
        #pragma unroll
        for (int ct = 0; ct < 8; ++ct)
            acc[ct] = __builtin_amdgcn_mfma_f32_16x16x32_bf16(ab, as_bf16x8(Bf[ct]), acc[ct], 0, 0, 0);
    };

    s16x8 Ba[8];
    i32x4 av0[2], av1[2], av2[2], av3[2];
    ldB(Ba, mbase);
    ldA(av0, mbase);
    ldA(av1, mbase + 32);
    ldA(av2, mbase + 64);
    ldA(av3, mbase + 96);

    #pragma unroll 1
    for (int i = 0; i < MITERS; i += 4) {
        int mr = i * 32;
        compute(Ba, av0, mr);
        ldB(Ba, mbase + ((mr + 32) & MM));
        ldA(av0, mbase + ((mr + 128) & MM));
        compute(Ba, av1, mr + 32);
        ldB(Ba, mbase + ((mr + 64) & MM));
        ldA(av1, mbase + ((mr + 160) & MM));
        compute(Ba, av2, mr + 64);
        ldB(Ba, mbase + ((mr + 96) & MM));
        ldA(av2, mbase + ((mr + 192) & MM));
        compute(Ba, av3, mr + 96);
        ldB(Ba, mbase + ((mr + 128) & MM));
        ldA(av3, mbase + ((mr + 224) & MM));
    }

    // z reduction over q (lanes lm, lm+16, lm+32, lm+48 hold partials of same row)
    z += __shfl_xor(z, 16);
    z += __shfl_xor(z, 32);

    int slice = b * SPLIT + mh;
    if (l < 16) Z[slice * 4096 + n0 + w * 16 + lm] = z;
    float* ub = U + ((long)slice * 4096 + n0 + w * 16) * 128;
    #pragma unroll
    for (int ct = 0; ct < 8; ++ct) {
        int col = ct * 16 + lm;
        #pragma unroll
        for (int r = 0; r < 4; ++r)
            ub[(q * 4 + r) * 128 + col] = acc[ct][r];
    }
}

// ---------------- k4: combine SPLIT=4 m-quarters + ELU ----------------
__global__ void k4_combine(const float* __restrict__ U, const float* __restrict__ Z,
                           float* __restrict__ out) {
    const long S = (long)4096 * 128;
    long g = (long)blockIdx.x * 256 + threadIdx.x;   // float4 index
    long off = g * 4;
    long nf = off >> 7;                               // b*4096+n
    int b = (int)(nf >> 12), n = (int)(nf & 4095), col = (int)(off & 127);
    long base0 = ((long)(b * 4) * 4096 + n) * 128 + col;
    f32x4 u0 = *(const f32x4*)(U + base0);
    f32x4 u1 = *(const f32x4*)(U + base0 + S);
    f32x4 u2 = *(const f32x4*)(U + base0 + 2 * S);
    f32x4 u3 = *(const f32x4*)(U + base0 + 3 * S);
    float zz = Z[(b * 4 + 0) * 4096 + n] + Z[(b * 4 + 1) * 4096 + n]
             + Z[(b * 4 + 2) * 4096 + n] + Z[(b * 4 + 3) * 4096 + n];
    f32x4 v;
    #pragma unroll
    for (int i = 0; i < 4; ++i) {
        float x = (u0[i] + u1[i] + u2[i] + u3[i]) / zz;
        v[i] = (x > 0.f) ? x : (expf(x) - 1.0f);
    }
    *(f32x4*)(out + off) = v;
}

extern "C" void kernel_launch(void* const* d_in, const int* in_sizes, int n_in,
                              void* d_out, int out_size, void* d_ws, size_t ws_size,
                              hipStream_t stream) {
    const float* h   = (const float*)d_in[0];
    const int*   adj = (const int*)d_in[1];
    const float* W   = (const float*)d_in[2];
    const float* a   = (const float*)d_in[3];
    float* out = (float*)d_out;

    char* ws = (char*)d_ws;
    short* WhT  = (short*)ws;                          // 4 MB  bf16 [b][col][n]
    short* WT   = (short*)(ws + 4194304);              // 64 KB bf16 [col][k]
    float* Wh1p = (float*)(ws + 4259840);              // 64 KB log2e*Wh@a1
    float* Tp   = (float*)(ws + 4325376);              // 64 KB log2e*Wh@a2
    float* Tmax = (float*)(ws + 4390912);              // 16 B (+pad)
    float* U    = (float*)(ws + 4391168);              // 32 MB (split=4)
    float* Z    = (float*)(ws + 4391168 + 33554432);   // 256 KB

    k0_wt<<<32, 256, 0, stream>>>(W, WT);
    k1_gemm<<<256, 256, 0, stream>>>(h, a, WT, WhT, Wh1p, Tp);
    k2_tmax<<<4, 256, 0, stream>>>(Tp, Tmax);
    k3_attn<4><<<1024, 256, 0, stream>>>(adj, WhT, Wh1p, Tp, Tmax, U, Z);
    k4_combine<<<2048, 256, 0, stream>>>(U, Z, out);
    (void)in_sizes; (void)n_in; (void)out_size; (void)ws_size;
}

// Round 4
// 440.180 us; speedup vs baseline: 1.1505x; 1.1505x over previous
//
#include <hip/hip_runtime.h>
#include <hip/hip_bf16.h>
#include <math.h>

typedef __attribute__((ext_vector_type(4))) float  f32x4;
typedef __attribute__((ext_vector_type(4))) int    i32x4;
typedef __attribute__((ext_vector_type(8))) short  s16x8;
typedef __attribute__((ext_vector_type(4))) short  s16x4;
typedef __attribute__((ext_vector_type(8))) __bf16 bf16x8;

#define LOG2E 1.4426950408889634f

__device__ __forceinline__ short f32_to_bf16_rne(float f) {
    unsigned u = __builtin_bit_cast(unsigned, f);
    u += 0x7fffu + ((u >> 16) & 1u);
    return (short)(u >> 16);
}
__device__ __forceinline__ int pack2_bf16(float f0, float f1) {
    unsigned u0 = __builtin_bit_cast(unsigned, f0) + 0x8000u;   // round-half-up
    unsigned u1 = __builtin_bit_cast(unsigned, f1) + 0x8000u;
    return (int)((u0 >> 16) | (u1 & 0xffff0000u));
}
__device__ __forceinline__ bf16x8 as_bf16x8(s16x8 v) {
    return __builtin_bit_cast(bf16x8, v);
}
__device__ __forceinline__ bf16x8 as_bf16x8(i32x4 v) {
    return __builtin_bit_cast(bf16x8, v);
}

// ---------------- k0: W (f32 [k][col]) -> WT bf16 [col][k] ----------------
__global__ void k0_wt(const float* __restrict__ W, short* __restrict__ WT) {
    int g = blockIdx.x * 256 + threadIdx.x;     // 0..8191
    int col = g >> 6;
    int k0 = (g & 63) * 4;
    s16x4 v;
    #pragma unroll
    for (int i = 0; i < 4; ++i) v[i] = f32_to_bf16_rne(W[(k0 + i) * 128 + col]);
    *(s16x4*)(WT + col * 256 + k0) = v;
}

// ---------------- k1: Wh = h@W (MFMA), emit WhT bf16 [b][col][n], Wh1', Wh2' ----------------
__global__ __launch_bounds__(256, 2) void k1_gemm(
    const float* __restrict__ h, const float* __restrict__ a,
    const short* __restrict__ WT,
    short* __restrict__ WhT, float* __restrict__ Wh1p, float* __restrict__ Tp)
{
    int l = threadIdx.x & 63;
    int w = threadIdx.x >> 6;
    int gw = blockIdx.x * 4 + w;
    int r0 = gw * 16;                  // global row base (b*4096+n), multiple of 16
    int lm = l & 15, q = l >> 4;

    f32x4 acc[8];
    #pragma unroll
    for (int ct = 0; ct < 8; ++ct) acc[ct] = (f32x4)0.0f;

    const float* hrow = h + (long)(r0 + lm) * 256;
    for (int kb = 0; kb < 8; ++kb) {
        int kbase = kb * 32 + q * 8;
        f32x4 h0 = *(const f32x4*)(hrow + kbase);
        f32x4 h1 = *(const f32x4*)(hrow + kbase + 4);
        s16x8 af;
        #pragma unroll
        for (int j = 0; j < 4; ++j) af[j] = f32_to_bf16_rne(h0[j]);
        #pragma unroll
        for (int j = 0; j < 4; ++j) af[4 + j] = f32_to_bf16_rne(h1[j]);
        bf16x8 afb = as_bf16x8(af);
        #pragma unroll
        for (int ct = 0; ct < 8; ++ct) {
            s16x8 bf = *(const s16x8*)(WT + (ct * 16 + lm) * 256 + kbase);
            acc[ct] = __builtin_amdgcn_mfma_f32_16x16x32_bf16(afb, as_bf16x8(bf), acc[ct], 0, 0, 0);
        }
    }

    int b = r0 >> 12;
    int nb = r0 & 4095;
    float p1[4] = {0.f, 0.f, 0.f, 0.f}, p2[4] = {0.f, 0.f, 0.f, 0.f};
    #pragma unroll
    for (int ct = 0; ct < 8; ++ct) {
        int col = ct * 16 + lm;
        float a1c = a[col], a2c = a[128 + col];
        s16x4 vv;
        #pragma unroll
        for (int r = 0; r < 4; ++r) {
            float v = acc[ct][r];
            p1[r] += v * a1c;
            p2[r] += v * a2c;
            vv[r] = f32_to_bf16_rne(v);
        }
        *(s16x4*)(WhT + ((long)(b * 128 + col) * 4096 + nb + q * 4)) = vv;
    }
    #pragma unroll
    for (int off = 1; off < 16; off <<= 1) {
        #pragma unroll
        for (int r = 0; r < 4; ++r) {
            p1[r] += __shfl_xor(p1[r], off);
            p2[r] += __shfl_xor(p2[r], off);
        }
    }
    if (lm == 0) {
        #pragma unroll
        for (int r = 0; r < 4; ++r) {
            int row = r0 + q * 4 + r;
            Wh1p[row] = LOG2E * p1[r];
            Tp[row]   = LOG2E * p2[r];
        }
    }
}

// ---------------- k2: per-batch max of Tp ----------------
__global__ void k2_tmax(const float* __restrict__ Tp, float* __restrict__ Tmax) {
    __shared__ float red[256];
    int b = blockIdx.x, t = threadIdx.x;
    float mx = -1e30f;
    for (int i = 0; i < 16; ++i) mx = fmaxf(mx, Tp[b * 4096 + t + i * 256]);
    red[t] = mx;
    __syncthreads();
    for (int s = 128; s > 0; s >>= 1) {
        if (t < s) red[t] = fmaxf(red[t], red[t + s]);
        __syncthreads();
    }
    if (t == 0) Tmax[b] = red[0];
}

// ---------------- k3: fused adj->LDS-bitmap prologue + R0 glds/barrier loop ----
// R1-R3 lessons: (R1) adj traffic as a separate kernel pass is a net loss;
// (R3) register-array prefetch pipelines get collapsed by the compiler
// (VGPR=64 => loads sunk to use); (R0/R2) the glds+single-barrier loop is the
// best-surviving structure. This version keeps R0's 128-m glds loop EXACTLY,
// but evicts adj from the loop: a prologue streams the block's whole adj slice
// (64 rows x 1024 m) with CONTIGUOUS 4-KB wave-bursts (DRAM-friendly, 16
// loads/wave in flight) and packs it to 1 bit/edge in an 8 KB LDS bitmap.
// The main loop then has NO HBM access: barrier drains only L2 glds (~300cy),
// hidden under ~1000cy of compute. If k3 still lands ~140us, the loop
// structure itself is the cost (ablation outcome), not memory.
// Bitmap layout: row r has 32 u32 words; u16 half l of word (l>>1) holds bits
// (c*4+j) = adj[r][256c + 4l + j]; words XOR-swizzled by (r&31) so 16 lanes
// reading different rows at the same logical word hit 16 distinct banks.
template <int SPLIT>
__global__ __launch_bounds__(256, 2) void k3_attn(
    const int* __restrict__ adj, const short* __restrict__ WhT,
    const float* __restrict__ Wh1p, const float* __restrict__ Tp,
    const float* __restrict__ Tmax,
    float* __restrict__ U, float* __restrict__ Z)
{
    const int MSLICE = 4096 / SPLIT;       // 1024
    const int MTILES = MSLICE / 128;       // 8
    __shared__ __align__(16) short tile[2][128 * 128];   // 64 KB B-tiles
    __shared__ __align__(16) float tps[4096 / SPLIT];    // 4 KB Tp slice
    __shared__ unsigned bm[64][32];                      // 8 KB adj bitmap

    int l = threadIdx.x & 63, w = threadIdx.x >> 6;
    int lm = l & 15, q = l >> 4;
    int bid = blockIdx.x;
    int p = bid & (4 * SPLIT - 1);         // (b, mh); 16 combos -> 2 per XCD
    int b  = p / SPLIT;                    // batch 0..3
    int mh = p & (SPLIT - 1);              // m-quarter 0..3
    int rg = bid / (4 * SPLIT);            // row-group 0..63
    int n0 = rg * 64;
    int mbase = mh * MSLICE;

    int n_lane = n0 + w * 16 + lm;
    int rrow = w * 16 + lm;                // block-local row for bitmap reads
    float sp = Wh1p[b * 4096 + n_lane];
    float xm = sp + Tmax[b];
    float Mrow = fmaxf(xm, 0.2f * xm);

    const short* whtb = WhT + (long)b * 128 * 4096;
    const float* tpsq = tps + q * 8;

    // ---- prologue: stream adj slice contiguously, pack to LDS bitmap ----
    // wave w loads rows w*16 .. w*16+15; per row: 4 x (64-lane x 16 B) = 4 KB
    // contiguous. Row groups of 4 keep 16 loads in flight (64 transient VGPRs).
    {
        const int* base = adj + ((long)(b * 4096 + n0 + w * 16) << 12) + mbase;
        unsigned short* bmh = (unsigned short*)bm;
        #pragma unroll 1
        for (int g = 0; g < 4; ++g) {
            i32x4 v[4][4];
            #pragma unroll
            for (int rr = 0; rr < 4; ++rr) {
                const int* rp = base + ((long)(g * 4 + rr) << 12) + l * 4;
                #pragma unroll
                for (int c = 0; c < 4; ++c) v[rr][c] = *(const i32x4*)(rp + c * 256);
            }
            #pragma unroll
            for (int rr = 0; rr < 4; ++rr) {
                unsigned bitsv = 0;
                #pragma unroll
                for (int c = 0; c < 4; ++c)
                    #pragma unroll
                    for (int j = 0; j < 4; ++j)
                        bitsv |= (v[rr][c][j] != 0) ? (1u << (c * 4 + j)) : 0u;
                int r = w * 16 + g * 4 + rr;
                bmh[r * 64 + (((l >> 1) ^ (r & 31)) << 1) + (l & 1)] = (unsigned short)bitsv;
            }
        }
    }

    // stage Tp slice to LDS (once): 1024 floats, one f32x4 per thread
    {
        const float* tg = Tp + b * 4096 + mbase;
        int i0 = threadIdx.x * 4;
        *(f32x4*)(tps + i0) = *(const f32x4*)(tg + i0);
    }

    f32x4 acc[8];
    #pragma unroll
    for (int ct = 0; ct < 8; ++ct) acc[ct] = (f32x4)0.0f;
    float z = 0.0f;

    // stage 128-m tile (R0-proven): 8 glds x 1 KB per wave; cols [w*32,w*32+32)
    auto stage = [&](short* dst, int m0) {
        int colw = w * 32;
        #pragma unroll
        for (int j = 0; j < 8; ++j) {
            int cb = colw + j * 4;
            int col = cb + q;
            int gch = lm ^ (col & 7);
            const short* gp = whtb + (long)col * 4096 + m0 + gch * 8;
            __builtin_amdgcn_global_load_lds(
                (const __attribute__((address_space(1))) void*)gp,
                (__attribute__((address_space(3))) void*)(dst + cb * 128), 16, 0, 0);
        }
    };
    // compute one 128-m tile trel (0..7); masks from LDS bitmap
    auto compute = [&](const short* buf, int trel) {
        int mrel = trel * 128;
        int shiftc = (trel >> 1) * 4;          // c = trel>>1 for all ks,q
        #pragma unroll
        for (int ks = 0; ks < 4; ++ks) {
            unsigned rd = bm[rrow][((16 * trel + 4 * ks + q) & 31) ^ (rrow & 31)];
            unsigned mask8 = ((rd >> shiftc) & 0xFu) | (((rd >> (16 + shiftc)) & 0xFu) << 4);
            f32x4 t0 = *(const f32x4*)(tpsq + mrel + ks * 32);
            f32x4 t1 = *(const f32x4*)(tpsq + mrel + ks * 32 + 4);
            i32x4 pk;
            float zs = 0.0f;
            #pragma unroll
            for (int half = 0; half < 2; ++half) {
                f32x4 t4 = half ? t1 : t0;
                float wv[4];
                #pragma unroll
                for (int j = 0; j < 4; ++j) {
                    float y = sp + t4[j];
                    float e = fmaxf(y, 0.2f * y) - Mrow;
                    float v = __builtin_amdgcn_exp2f(e);
                    v = (mask8 & (1u << (half * 4 + j))) ? v : 0.0f;
                    zs += v; wv[j] = v;
                }
                pk[half * 2]     = pack2_bf16(wv[0], wv[1]);
                pk[half * 2 + 1] = pack2_bf16(wv[2], wv[3]);
            }
            z += zs;
            bf16x8 ab = as_bf16x8(pk);
            #pragma unroll
            for (int ct = 0; ct < 8; ++ct) {
                int col = ct * 16 + lm;
                int pos = (ks * 4 + q) ^ (col & 7);
                s16x8 bf = *(const s16x8*)(buf + col * 128 + pos * 8);
                acc[ct] = __builtin_amdgcn_mfma_f32_16x16x32_bf16(ab, as_bf16x8(bf), acc[ct], 0, 0, 0);
            }
        }
    };

    stage(tile[0], mbase);
    __syncthreads();

    #pragma unroll 1
    for (int t = 0; t < MTILES; t += 2) {
        stage(tile[1], mbase + ((t + 1) & (MTILES - 1)) * 128);
        __builtin_amdgcn_sched_barrier(0);
        compute(tile[0], t);
        __syncthreads();
        stage(tile[0], mbase + ((t + 2) & (MTILES - 1)) * 128);
        __builtin_amdgcn_sched_barrier(0);
        compute(tile[1], t + 1);
        __syncthreads();
    }

    // z reduction over q (lanes lm, lm+16, lm+32, lm+48 hold partials of same row)
    z += __shfl_xor(z, 16);
    z += __shfl_xor(z, 32);

    int slice = b * SPLIT + mh;
    if (l < 16) Z[slice * 4096 + n0 + w * 16 + lm] = z;
    float* ub = U + ((long)slice * 4096 + n0 + w * 16) * 128;
    #pragma unroll
    for (int ct = 0; ct < 8; ++ct) {
        int col = ct * 16 + lm;
        #pragma unroll
        for (int r = 0; r < 4; ++r)
            ub[(q * 4 + r) * 128 + col] = acc[ct][r];
    }
}

// ---------------- k4: combine SPLIT=4 m-quarters + ELU ----------------
__global__ void k4_combine(const float* __restrict__ U, const float* __restrict__ Z,
                           float* __restrict__ out) {
    const long S = (long)4096 * 128;
    long g = (long)blockIdx.x * 256 + threadIdx.x;   // float4 index
    long off = g * 4;
    long nf = off >> 7;                               // b*4096+n
    int b = (int)(nf >> 12), n = (int)(nf & 4095), col = (int)(off & 127);
    long base0 = ((long)(b * 4) * 4096 + n) * 128 + col;
    f32x4 u0 = *(const f32x4*)(U + base0);
    f32x4 u1 = *(const f32x4*)(U + base0 + S);
    f32x4 u2 = *(const f32x4*)(U + base0 + 2 * S);
    f32x4 u3 = *(const f32x4*)(U + base0 + 3 * S);
    float zz = Z[(b * 4 + 0) * 4096 + n] + Z[(b * 4 + 1) * 4096 + n]
             + Z[(b * 4 + 2) * 4096 + n] + Z[(b * 4 + 3) * 4096 + n];
    f32x4 v;
    #pragma unroll
    for (int i = 0; i < 4; ++i) {
        float x = (u0[i] + u1[i] + u2[i] + u3[i]) / zz;
        v[i] = (x > 0.f) ? x : (expf(x) - 1.0f);
    }
    *(f32x4*)(out + off) = v;
}

extern "C" void kernel_launch(void* const* d_in, const int* in_sizes, int n_in,
                              void* d_out, int out_size, void* d_ws, size_t ws_size,
                              hipStream_t stream) {
    const float* h   = (const float*)d_in[0];
    const int*   adj = (const int*)d_in[1];
    const float* W   = (const float*)d_in[2];
    const float* a   = (const float*)d_in[3];
    float* out = (float*)d_out;

    char* ws = (char*)d_ws;
    short* WhT  = (short*)ws;                          // 4 MB  bf16 [b][col][n]
    short* WT   = (short*)(ws + 4194304);              // 64 KB bf16 [col][k]
    float* Wh1p = (float*)(ws + 4259840);              // 64 KB log2e*Wh@a1
    float* Tp   = (float*)(ws + 4325376);              // 64 KB log2e*Wh@a2
    float* Tmax = (float*)(ws + 4390912);              // 16 B (+pad)
    float* U    = (float*)(ws + 4391168);              // 32 MB (split=4)
    float* Z    = (float*)(ws + 4391168 + 33554432);   // 256 KB

    k0_wt<<<32, 256, 0, stream>>>(W, WT);
    k1_gemm<<<256, 256, 0, stream>>>(h, a, WT, WhT, Wh1p, Tp);
    k2_tmax<<<4, 256, 0, stream>>>(Tp, Tmax);
    k3_attn<4><<<1024, 256, 0, stream>>>(adj, WhT, Wh1p, Tp, Tmax, U, Z);
    k4_combine<<<2048, 256, 0, stream>>>(U, Z, out);
    (void)in_sizes; (void)n_in; (void)out_size; (void)ws_size;
}

// Round 7
// 415.468 us; speedup vs baseline: 1.2189x; 1.0595x over previous
//
#include <hip/hip_runtime.h>
#include <hip/hip_bf16.h>
#include <math.h>

typedef __attribute__((ext_vector_type(4))) float  f32x4;
typedef __attribute__((ext_vector_type(4))) int    i32x4;
typedef __attribute__((ext_vector_type(8))) short  s16x8;
typedef __attribute__((ext_vector_type(4))) short  s16x4;
typedef __attribute__((ext_vector_type(8))) __bf16 bf16x8;

#define LOG2E 1.4426950408889634f

__device__ __forceinline__ short f32_to_bf16_rne(float f) {
    unsigned u = __builtin_bit_cast(unsigned, f);
    u += 0x7fffu + ((u >> 16) & 1u);
    return (short)(u >> 16);
}
__device__ __forceinline__ int pack2_bf16(float f0, float f1) {
    unsigned u0 = __builtin_bit_cast(unsigned, f0) + 0x8000u;   // round-half-up
    unsigned u1 = __builtin_bit_cast(unsigned, f1) + 0x8000u;
    return (int)((u0 >> 16) | (u1 & 0xffff0000u));
}
__device__ __forceinline__ bf16x8 as_bf16x8(s16x8 v) {
    return __builtin_bit_cast(bf16x8, v);
}
__device__ __forceinline__ bf16x8 as_bf16x8(i32x4 v) {
    return __builtin_bit_cast(bf16x8, v);
}

// ---------------- k0: W (f32 [k][col]) -> WT bf16 [col][k] ----------------
__global__ void k0_wt(const float* __restrict__ W, short* __restrict__ WT) {
    int g = blockIdx.x * 256 + threadIdx.x;     // 0..8191
    int col = g >> 6;
    int k0 = (g & 63) * 4;
    s16x4 v;
    #pragma unroll
    for (int i = 0; i < 4; ++i) v[i] = f32_to_bf16_rne(W[(k0 + i) * 128 + col]);
    *(s16x4*)(WT + col * 256 + k0) = v;
}

// ---------------- k1: Wh = h@W (MFMA), emit WhT bf16 [b][col][n], Wh1', Wh2' ----------------
__global__ __launch_bounds__(256, 2) void k1_gemm(
    const float* __restrict__ h, const float* __restrict__ a,
    const short* __restrict__ WT,
    short* __restrict__ WhT, float* __restrict__ Wh1p, float* __restrict__ Tp)
{
    int l = threadIdx.x & 63;
    int w = threadIdx.x >> 6;
    int gw = blockIdx.x * 4 + w;
    int r0 = gw * 16;                  // global row base (b*4096+n), multiple of 16
    int lm = l & 15, q = l >> 4;

    f32x4 acc[8];
    #pragma unroll
    for (int ct = 0; ct < 8; ++ct) acc[ct] = (f32x4)0.0f;

    const float* hrow = h + (long)(r0 + lm) * 256;
    for (int kb = 0; kb < 8; ++kb) {
        int kbase = kb * 32 + q * 8;
        f32x4 h0 = *(const f32x4*)(hrow + kbase);
        f32x4 h1 = *(const f32x4*)(hrow + kbase + 4);
        s16x8 af;
        #pragma unroll
        for (int j = 0; j < 4; ++j) af[j] = f32_to_bf16_rne(h0[j]);
        #pragma unroll
        for (int j = 0; j < 4; ++j) af[4 + j] = f32_to_bf16_rne(h1[j]);
        bf16x8 afb = as_bf16x8(af);
        #pragma unroll
        for (int ct = 0; ct < 8; ++ct) {
            s16x8 bf = *(const s16x8*)(WT + (ct * 16 + lm) * 256 + kbase);
            acc[ct] = __builtin_amdgcn_mfma_f32_16x16x32_bf16(afb, as_bf16x8(bf), acc[ct], 0, 0, 0);
        }
    }

    int b = r0 >> 12;
    int nb = r0 & 4095;
    float p1[4] = {0.f, 0.f, 0.f, 0.f}, p2[4] = {0.f, 0.f, 0.f, 0.f};
    #pragma unroll
    for (int ct = 0; ct < 8; ++ct) {
        int col = ct * 16 + lm;
        float a1c = a[col], a2c = a[128 + col];
        s16x4 vv;
        #pragma unroll
        for (int r = 0; r < 4; ++r) {
            float v = acc[ct][r];
            p1[r] += v * a1c;
            p2[r] += v * a2c;
            vv[r] = f32_to_bf16_rne(v);
        }
        *(s16x4*)(WhT + ((long)(b * 128 + col) * 4096 + nb + q * 4)) = vv;
    }
    #pragma unroll
    for (int off = 1; off < 16; off <<= 1) {
        #pragma unroll
        for (int r = 0; r < 4; ++r) {
            p1[r] += __shfl_xor(p1[r], off);
            p2[r] += __shfl_xor(p2[r], off);
        }
    }
    if (lm == 0) {
        #pragma unroll
        for (int r = 0; r < 4; ++r) {
            int row = r0 + q * 4 + r;
            Wh1p[row] = LOG2E * p1[r];
            Tp[row]   = LOG2E * p2[r];
        }
    }
}

// ---------------- k2: per-batch max of Tp ----------------
__global__ void k2_tmax(const float* __restrict__ Tp, float* __restrict__ Tmax) {
    __shared__ float red[256];
    int b = blockIdx.x, t = threadIdx.x;
    float mx = -1e30f;
    for (int i = 0; i < 16; ++i) mx = fmaxf(mx, Tp[b * 4096 + t + i * 256]);
    red[t] = mx;
    __syncthreads();
    for (int s = 128; s > 0; s >>= 1) {
        if (t < s) red[t] = fmaxf(red[t], red[t + s]);
        __syncthreads();
    }
    if (t == 0) Tmax[b] = red[0];
}

// ---------------- k3: R0 structure + COUNTED vmcnt (no vmcnt(0) drain) --------
// R5/R6 failed with BIT-IDENTICAL absmax across different fence variants =>
// deterministic logic bug, not a race: the (b,mh) decode masked with
// 2*SPLIT-1=3 instead of 4*SPLIT-1=7 -- batches 2-3 never computed and
// rg ran 0..127 (n0 up to 8128, OOB). Fixed decode below; schedule unchanged.
// Count arithmetic (pinned [S][A] order per phase, steady state): at sub-phase
// k's wait the queue is [A_k+1(8), S_k+1(8), A_k+2(8), S_k+2(8), A_k+3(8)]=40;
// vmcnt(24) retires exactly A_k+1, S_k+1 -- the adj regs + tile glds that
// compute(k+1) needs -- while 24 newer ops stay in flight ACROSS the barrier.
template <int SPLIT>
__global__ __launch_bounds__(256, 2) void k3_attn(
    const int* __restrict__ adj, const short* __restrict__ WhT,
    const float* __restrict__ Wh1p, const float* __restrict__ Tp,
    const float* __restrict__ Tmax,
    float* __restrict__ U, float* __restrict__ Z)
{
    const int MSLICE = 4096 / SPLIT;       // 2048
    const int MTILES = MSLICE / 128;       // 16
    __shared__ __align__(16) short tile[2][128 * 128];   // 64 KB B-tiles
    __shared__ __align__(16) float tps[4096 / SPLIT];    // 8 KB Tp slice

    int l = threadIdx.x & 63, w = threadIdx.x >> 6;
    int lm = l & 15, q = l >> 4;
    int bid = blockIdx.x;
    int p8 = bid & (4 * SPLIT - 1);        // (b, mh): 4 batches x SPLIT halves = 8
    int b  = p8 / SPLIT;                   // batch 0..3
    int mh = p8 % SPLIT;                   // m-half 0..1
    int rg = bid / (4 * SPLIT);            // row-group 0..63
    int n0 = rg * 64;
    int mbase = mh * MSLICE;

    int n_lane = n0 + w * 16 + lm;
    float sp = Wh1p[b * 4096 + n_lane];
    float xm = sp + Tmax[b];
    float Mrow = fmaxf(xm, 0.2f * xm);

    const int*   adjrow = adj + ((long)(b * 4096 + n_lane) << 12) + q * 8;
    const short* whtb   = WhT + (long)b * 128 * 4096;
    const float* tpsq   = tps + q * 8;

    // stage Tp slice to LDS (once)
    {
        const float* tg = Tp + b * 4096 + mbase;
        int i0 = threadIdx.x * 4;
        *(f32x4*)(tps + i0)        = *(const f32x4*)(tg + i0);
        *(f32x4*)(tps + i0 + 1024) = *(const f32x4*)(tg + i0 + 1024);
    }

    f32x4 acc[8];
    #pragma unroll
    for (int ct = 0; ct < 8; ++ct) acc[ct] = (f32x4)0.0f;
    float z = 0.0f;

    auto stage = [&](short* dst, int m0) {       // 8 glds (vmcnt ops), L2 source
        int colw = w * 32;
        #pragma unroll
        for (int j = 0; j < 8; ++j) {
            int cb = colw + j * 4;
            int col = cb + q;
            int gch = lm ^ (col & 7);
            const short* gp = whtb + (long)col * 4096 + m0 + gch * 8;
            __builtin_amdgcn_global_load_lds(
                (const __attribute__((address_space(1))) void*)gp,
                (__attribute__((address_space(3))) void*)(dst + cb * 128), 16, 0, 0);
        }
    };
    auto ldadj = [&](i32x4* aj, int m0) {        // 8 dwordx4 loads (vmcnt ops), HBM
        #pragma unroll
        for (int ks = 0; ks < 4; ++ks) {
            aj[2 * ks]     = *(const i32x4*)(adjrow + m0 + ks * 32);
            aj[2 * ks + 1] = *(const i32x4*)(adjrow + m0 + ks * 32 + 4);
        }
    };
    auto compute = [&](const short* buf, const i32x4* aj, int mrel) {
        #pragma unroll
        for (int ks = 0; ks < 4; ++ks) {
            f32x4 t0 = *(const f32x4*)(tpsq + mrel + ks * 32);
            f32x4 t1 = *(const f32x4*)(tpsq + mrel + ks * 32 + 4);
            i32x4 pk;
            float zs = 0.0f;
            #pragma unroll
            for (int half = 0; half < 2; ++half) {
                i32x4 a4 = aj[2 * ks + half];
                f32x4 t4 = half ? t1 : t0;
                float wv[4];
                #pragma unroll
                for (int j = 0; j < 4; ++j) {
                    float y = sp + t4[j];
                    float e = fmaxf(y, 0.2f * y) - Mrow;
                    float v = __builtin_amdgcn_exp2f(e);
                    v = (a4[j] != 0) ? v : 0.0f;
                    zs += v; wv[j] = v;
                }
                pk[half * 2]     = pack2_bf16(wv[0], wv[1]);
                pk[half * 2 + 1] = pack2_bf16(wv[2], wv[3]);
            }
            z += zs;
            bf16x8 ab = as_bf16x8(pk);
            #pragma unroll
            for (int ct = 0; ct < 8; ++ct) {
                int col = ct * 16 + lm;
                int pos = (ks * 4 + q) ^ (col & 7);
                s16x8 bf = *(const s16x8*)(buf + col * 128 + pos * 8);
                acc[ct] = __builtin_amdgcn_mfma_f32_16x16x32_bf16(ab, as_bf16x8(bf), acc[ct], 0, 0, 0);
            }
        }
    };

    // one sub-phase. Issue-order fences are load-bearing: vmcnt FIFO math
    // assumes [S][A] per phase; end-barrier fence keeps next phase's glds out
    // of this tile's read window.
    #define SUBPHASE(CBUF, SBUF, AJ_LD, AJ_USE, TC, TS, TA)                    \
        stage(SBUF, mbase + ((TS) & (MTILES - 1)) * 128);                      \
        __builtin_amdgcn_sched_barrier(0);                                     \
        ldadj(AJ_LD, mbase + ((TA) & (MTILES - 1)) * 128);                     \
        __builtin_amdgcn_sched_barrier(0);                                     \
        asm volatile("s_waitcnt vmcnt(24)" ::: "memory");                      \
        __builtin_amdgcn_s_barrier();                                          \
        __builtin_amdgcn_sched_barrier(0);                                     \
        compute(CBUF, AJ_USE, (TC) * 128);                                     \
        __builtin_amdgcn_sched_barrier(0);                                     \
        __builtin_amdgcn_s_barrier();                                          \
        __builtin_amdgcn_sched_barrier(0);

    i32x4 ajA[8], ajB[8], ajC[8], ajD[8];
    stage(tile[0], mbase);
    __builtin_amdgcn_sched_barrier(0);
    ldadj(ajA, mbase);
    ldadj(ajB, mbase + 128);
    __builtin_amdgcn_sched_barrier(0);
    asm volatile("s_waitcnt vmcnt(0) lgkmcnt(0)" ::: "memory");  // covers tps too
    __builtin_amdgcn_s_barrier();
    __builtin_amdgcn_sched_barrier(0);

    #pragma unroll 1
    for (int t = 0; t < MTILES; t += 4) {
        SUBPHASE(tile[0], tile[1], ajC, ajA, t,     t + 1, t + 2)
        SUBPHASE(tile[1], tile[0], ajD, ajB, t + 1, t + 2, t + 3)
        SUBPHASE(tile[0], tile[1], ajA, ajC, t + 2, t + 3, t + 4)
        SUBPHASE(tile[1], tile[0], ajB, ajD, t + 3, t + 4, t + 5)
    }
    #undef SUBPHASE

    // z reduction over q (lanes lm, lm+16, lm+32, lm+48 hold partials of same row)
    z += __shfl_xor(z, 16);
    z += __shfl_xor(z, 32);

    int slice = b * SPLIT + mh;
    if (l < 16) Z[slice * 4096 + n0 + w * 16 + lm] = z;
    float* ub = U + ((long)slice * 4096 + n0 + w * 16) * 128;
    #pragma unroll
    for (int ct = 0; ct < 8; ++ct) {
        int col = ct * 16 + lm;
        #pragma unroll
        for (int r = 0; r < 4; ++r)
            ub[(q * 4 + r) * 128 + col] = acc[ct][r];
    }
}

// ---------------- k4: combine split-m halves + ELU ----------------
__global__ void k4_combine(const float* __restrict__ U, const float* __restrict__ Z,
                           float* __restrict__ out) {
    long g = (long)blockIdx.x * 256 + threadIdx.x;   // float4 index
    long off = g * 4;
    long nf = off >> 7;                               // b*4096+n
    int b = (int)(nf >> 12), n = (int)(nf & 4095), col = (int)(off & 127);
    long base0 = ((long)(b * 2) * 4096 + n) * 128 + col;
    f32x4 u0 = *(const f32x4*)(U + base0);
    f32x4 u1 = *(const f32x4*)(U + base0 + (long)4096 * 128);
    float zz = Z[(b * 2) * 4096 + n] + Z[(b * 2 + 1) * 4096 + n];
    f32x4 v;
    #pragma unroll
    for (int i = 0; i < 4; ++i) {
        float x = (u0[i] + u1[i]) / zz;
        v[i] = (x > 0.f) ? x : (expf(x) - 1.0f);
    }
    *(f32x4*)(out + off) = v;
}

extern "C" void kernel_launch(void* const* d_in, const int* in_sizes, int n_in,
                              void* d_out, int out_size, void* d_ws, size_t ws_size,
                              hipStream_t stream) {
    const float* h   = (const float*)d_in[0];
    const int*   adj = (const int*)d_in[1];
    const float* W   = (const float*)d_in[2];
    const float* a   = (const float*)d_in[3];
    float* out = (float*)d_out;

    char* ws = (char*)d_ws;
    short* WhT  = (short*)ws;                          // 4 MB  bf16 [b][col][n]
    short* WT   = (short*)(ws + 4194304);              // 64 KB bf16 [col][k]
    float* Wh1p = (float*)(ws + 4259840);              // 64 KB log2e*Wh@a1
    float* Tp   = (float*)(ws + 4325376);              // 64 KB log2e*Wh@a2
    float* Tmax = (float*)(ws + 4390912);              // 16 B (+pad)
    float* U    = (float*)(ws + 4391168);              // 16 MB (split=2)
    float* Z    = (float*)(ws + 4391168 + 16777216);   // 128 KB

    k0_wt<<<32, 256, 0, stream>>>(W, WT);
    k1_gemm<<<256, 256, 0, stream>>>(h, a, WT, WhT, Wh1p, Tp);
    k2_tmax<<<4, 256, 0, stream>>>(Tp, Tmax);
    k3_attn<2><<<512, 256, 0, stream>>>(adj, WhT, Wh1p, Tp, Tmax, U, Z);
    k4_combine<<<2048, 256, 0, stream>>>(U, Z, out);
    (void)in_sizes; (void)n_in; (void)out_size; (void)ws_size;
}